// Round 4
// baseline (13242.932 us; speedup 1.0000x reference)
//
#include <hip/hip_runtime.h>

#define HH 128
constexpr int cN   = 200000;
constexpr int cE   = 800000;
constexpr int cNS  = 400000;
constexpr int cES  = 1600000;
constexpr int cB   = 512;
constexpr int cPPG = 8;
constexpr int cPT  = 4;
constexpr int cNP  = cB * cPPG;     // 4096 patches
constexpr int cNF  = 64;
constexpr int cNE  = 16;
constexpr int cRW  = 16;
constexpr int cPRW = 16;
constexpr int cL   = 4;
constexpr int cCH  = cNS / 4;       // 100000 dst-rows per context agg chunk

__device__ __forceinline__ float b2f(unsigned short b) {
    return __uint_as_float(((unsigned int)b) << 16);
}
__device__ __forceinline__ unsigned short f2b(float f) {
    unsigned int u = __float_as_uint(f);
    return (unsigned short)((u + 0x7fffu + ((u >> 16) & 1u)) >> 16);  // RNE
}

// ---------------- diagnostic: fill out with a constant (encodes ws_size MB) ----------------
__global__ void k_diag(float* __restrict__ out, int n, float val) {
    int gid = blockIdx.x * 256 + threadIdx.x;
    if (gid < n) out[gid] = val;
}

// ---------------- zero-fill (float4, grid-stride) ----------------
__global__ void k_zero(float4* __restrict__ p, size_t n4) {
    size_t gid = (size_t)blockIdx.x * 256 + threadIdx.x;
    size_t stride = (size_t)gridDim.x * 256;
    for (size_t i = gid; i < n4; i += stride) p[i] = make_float4(0.f, 0.f, 0.f, 0.f);
}

// ---------------- node encoder: x0 = x@Win + bin + rw@Wrw + brw (f32 out) ----------------
__global__ void k_node_encode(const float* __restrict__ x, const float* __restrict__ rw,
                              const float* __restrict__ Win, const float* __restrict__ bin,
                              const float* __restrict__ Wrw, const float* __restrict__ brw,
                              float* __restrict__ x0) {
    __shared__ float sx[cNF];
    __shared__ float srw[cRW];
    int node = blockIdx.x;
    int t = threadIdx.x;  // 128
    if (t < cNF) sx[t] = x[(size_t)node * cNF + t];
    else if (t < cNF + cRW) srw[t - cNF] = rw[(size_t)node * cRW + (t - cNF)];
    __syncthreads();
    float acc = bin[t] + brw[t];
#pragma unroll
    for (int k = 0; k < cNF; k++) acc += sx[k] * Win[k * HH + t];
#pragma unroll
    for (int k = 0; k < cRW; k++) acc += srw[k] * Wrw[k * HH + t];
    x0[(size_t)node * HH + t] = acc;
}

// ---------------- gather rows f32 -> bf16: dst[i] = bf16(src[map[i]]) ----------------
__global__ void k_gather_bf16(const float* __restrict__ src, const int* __restrict__ map,
                              unsigned short* __restrict__ dst, int nrows) {
    int gid = blockIdx.x * 256 + threadIdx.x;
    if (gid >= nrows * HH) return;
    int r = gid >> 7, h = gid & 127;
    dst[gid] = f2b(src[(size_t)map[r] * HH + h]);
}

// ---------------- target message (all f32): agg[dst] += (h[src]+relu(ea@We+be))*w ----------------
__global__ void k_msg_f32(const float* __restrict__ h_in, const int* __restrict__ src,
                          const int* __restrict__ dst, const float* __restrict__ eattr,
                          const float* __restrict__ ew, const float* __restrict__ We,
                          const float* __restrict__ be, float* __restrict__ agg, int ne) {
    int gid = blockIdx.x * 256 + threadIdx.x;
    if (gid >= ne * HH) return;
    int e = gid >> 7, hh = gid & 127;
    float w = ew[e];
    const float* ea = eattr + (size_t)e * cNE;
    float eh = be[hh];
#pragma unroll
    for (int k = 0; k < cNE; k++) eh += ea[k] * We[k * HH + hh];
    eh = fmaxf(eh, 0.f);
    float msg = (h_in[(size_t)src[e] * HH + hh] + eh) * w;
    atomicAdd(&agg[(size_t)dst[e] * HH + hh], msg);
}

// ---------------- context message: bf16 h, f32 agg chunk over dst rows [r0,r1) ----------------
__global__ void k_msg_ctx(const unsigned short* __restrict__ h_in, const int* __restrict__ src,
                          const int* __restrict__ dst, const float* __restrict__ eattr,
                          const int* __restrict__ emap, const float* __restrict__ ew,
                          const float* __restrict__ We, const float* __restrict__ be,
                          float* __restrict__ agg, int r0, int r1, int ne) {
    int gid = blockIdx.x * 256 + threadIdx.x;
    if (gid >= ne * HH) return;  // ne*HH = 204.8M < 2^31
    int e = gid >> 7, hh = gid & 127;
    int d = dst[e];
    if (d < r0 || d >= r1) return;   // wave-uniform (128 threads per edge)
    int ai = emap[e];
    float w = ew[ai];
    const float* ea = eattr + (size_t)ai * cNE;
    float eh = be[hh];
#pragma unroll
    for (int k = 0; k < cNE; k++) eh += ea[k] * We[k * HH + hh];
    eh = fmaxf(eh, 0.f);
    float msg = (b2f(h_in[(size_t)src[e] * HH + hh]) + eh) * w;
    atomicAdd(&agg[(size_t)(d - r0) * HH + hh], msg);
}

// ---------------- target layer GEMM: h = relu(concat(h,agg)@W+b), in-place f32 ----------------
__global__ void k_layer_gemm(float* __restrict__ h, const float* __restrict__ agg,
                             const float* __restrict__ W, const float* __restrict__ b) {
    __shared__ float a[32][2 * HH];  // 32 KB
    int base = blockIdx.x * 32;
    int t = threadIdx.x;  // 256
    for (int i = t; i < 32 * 2 * HH; i += 256) {
        int r = i >> 8, c = i & 255;
        int row = base + r;
        a[r][c] = (c < HH) ? h[(size_t)row * HH + c] : agg[(size_t)row * HH + (c - HH)];
    }
    __syncthreads();
    int cg = t & 31;   // cols cg*4..+3
    int rg = t >> 5;   // rows rg*4..+3
    float acc[4][4];
#pragma unroll
    for (int r = 0; r < 4; r++)
#pragma unroll
        for (int c = 0; c < 4; c++) acc[r][c] = 0.f;
    for (int k = 0; k < 2 * HH; k += 4) {
        float4 av[4];
#pragma unroll
        for (int r = 0; r < 4; r++) av[r] = *(const float4*)&a[rg * 4 + r][k];
        float4 wv[4];
#pragma unroll
        for (int kk = 0; kk < 4; kk++) wv[kk] = *(const float4*)&W[(size_t)(k + kk) * HH + cg * 4];
#pragma unroll
        for (int r = 0; r < 4; r++) {
            float a0 = av[r].x, a1 = av[r].y, a2 = av[r].z, a3 = av[r].w;
            acc[r][0] += a0 * wv[0].x + a1 * wv[1].x + a2 * wv[2].x + a3 * wv[3].x;
            acc[r][1] += a0 * wv[0].y + a1 * wv[1].y + a2 * wv[2].y + a3 * wv[3].y;
            acc[r][2] += a0 * wv[0].z + a1 * wv[1].z + a2 * wv[2].z + a3 * wv[3].z;
            acc[r][3] += a0 * wv[0].w + a1 * wv[1].w + a2 * wv[2].w + a3 * wv[3].w;
        }
    }
    float4 bv = *(const float4*)&b[cg * 4];
#pragma unroll
    for (int r = 0; r < 4; r++) {
        int row = base + rg * 4 + r;
        float4 o;
        o.x = fmaxf(acc[r][0] + bv.x, 0.f);
        o.y = fmaxf(acc[r][1] + bv.y, 0.f);
        o.z = fmaxf(acc[r][2] + bv.z, 0.f);
        o.w = fmaxf(acc[r][3] + bv.w, 0.f);
        *(float4*)&h[(size_t)row * HH + cg * 4] = o;
    }
}

// ---------------- context layer GEMM: rows [r0,r0+CH), bf16 old-h + f32 agg -> bf16 new-h ----------------
__global__ void k_layer_gemm_ctx(const unsigned short* __restrict__ hold,
                                 const float* __restrict__ aggc, int r0,
                                 unsigned short* __restrict__ hnew,
                                 const float* __restrict__ W, const float* __restrict__ b) {
    __shared__ float a[32][2 * HH];  // 32 KB
    int base = r0 + blockIdx.x * 32;
    int t = threadIdx.x;  // 256
    for (int i = t; i < 32 * 2 * HH; i += 256) {
        int r = i >> 8, c = i & 255;
        int row = base + r;
        a[r][c] = (c < HH) ? b2f(hold[(size_t)row * HH + c])
                           : aggc[(size_t)(row - r0) * HH + (c - HH)];
    }
    __syncthreads();
    int cg = t & 31;
    int rg = t >> 5;
    float acc[4][4];
#pragma unroll
    for (int r = 0; r < 4; r++)
#pragma unroll
        for (int c = 0; c < 4; c++) acc[r][c] = 0.f;
    for (int k = 0; k < 2 * HH; k += 4) {
        float4 av[4];
#pragma unroll
        for (int r = 0; r < 4; r++) av[r] = *(const float4*)&a[rg * 4 + r][k];
        float4 wv[4];
#pragma unroll
        for (int kk = 0; kk < 4; kk++) wv[kk] = *(const float4*)&W[(size_t)(k + kk) * HH + cg * 4];
#pragma unroll
        for (int r = 0; r < 4; r++) {
            float a0 = av[r].x, a1 = av[r].y, a2 = av[r].z, a3 = av[r].w;
            acc[r][0] += a0 * wv[0].x + a1 * wv[1].x + a2 * wv[2].x + a3 * wv[3].x;
            acc[r][1] += a0 * wv[0].y + a1 * wv[1].y + a2 * wv[2].y + a3 * wv[3].y;
            acc[r][2] += a0 * wv[0].z + a1 * wv[1].z + a2 * wv[2].z + a3 * wv[3].z;
            acc[r][3] += a0 * wv[0].w + a1 * wv[1].w + a2 * wv[2].w + a3 * wv[3].w;
        }
    }
    float4 bv = *(const float4*)&b[cg * 4];
#pragma unroll
    for (int r = 0; r < 4; r++) {
        int row = base + rg * 4 + r;
        ushort4 o;
        o.x = f2b(fmaxf(acc[r][0] + bv.x, 0.f));
        o.y = f2b(fmaxf(acc[r][1] + bv.y, 0.f));
        o.z = f2b(fmaxf(acc[r][2] + bv.z, 0.f));
        o.w = f2b(fmaxf(acc[r][3] + bv.w, 0.f));
        *(ushort4*)&hnew[(size_t)row * HH + cg * 4] = o;
    }
}

// ---------------- segmented mean over sorted batch, f32 src (optional row map) ----------------
__global__ void k_seg_mean_f32(const float* __restrict__ src, const int* __restrict__ map,
                               const int* __restrict__ batch, float* __restrict__ out, int nrows) {
    int b = blockIdx.x;
    int t = threadIdx.x;  // 128
    int lo = 0, hi = nrows;
    while (lo < hi) { int m = (lo + hi) >> 1; if (batch[m] < b) lo = m + 1; else hi = m; }
    int s = lo;
    hi = nrows;
    while (lo < hi) { int m = (lo + hi) >> 1; if (batch[m] < b + 1) lo = m + 1; else hi = m; }
    int e = lo;
    float acc = 0.f;
    for (int r = s; r < e; r++) {
        size_t row = map ? (size_t)map[r] : (size_t)r;
        acc += src[row * HH + t];
    }
    out[(size_t)b * HH + t] = acc / fmaxf((float)(e - s), 1.f);
}

// ---------------- segmented mean, bf16 src, identity map ----------------
__global__ void k_seg_mean_bf16(const unsigned short* __restrict__ src,
                                const int* __restrict__ batch, float* __restrict__ out, int nrows) {
    int b = blockIdx.x;
    int t = threadIdx.x;  // 128
    int lo = 0, hi = nrows;
    while (lo < hi) { int m = (lo + hi) >> 1; if (batch[m] < b) lo = m + 1; else hi = m; }
    int s = lo;
    hi = nrows;
    while (lo < hi) { int m = (lo + hi) >> 1; if (batch[m] < b + 1) lo = m + 1; else hi = m; }
    int e = lo;
    float acc = 0.f;
    for (int r = s; r < e; r++) acc += b2f(src[(size_t)r * HH + t]);
    out[(size_t)b * HH + t] = acc / fmaxf((float)(e - s), 1.f);
}

// ---------------- cond = emb_ctx + (patch_pe[tidx]@Wprw+bprw); out0 = emb_tgt ----------------
__global__ void k_cond(const float* __restrict__ mctx, const float* __restrict__ mtgt,
                       const int* __restrict__ cidx, const int* __restrict__ tgt_idxs,
                       const float* __restrict__ ppe, const float* __restrict__ Wprw,
                       const float* __restrict__ bprw, float* __restrict__ cond,
                       float* __restrict__ out0) {
    int r = blockIdx.x;   // 0..2047
    int t = threadIdx.x;  // 128
    int bg = r >> 2, tt = r & 3;
    int ti = tgt_idxs[bg * cPT + tt] + bg * cPPG;
    int ci = cidx[bg] + bg * cPPG;
    __shared__ float pe[cPRW];
    if (t < cPRW) pe[t] = ppe[(size_t)ti * cPRW + t];
    __syncthreads();
    float acc = bprw[t];
#pragma unroll
    for (int k = 0; k < cPRW; k++) acc += pe[k] * Wprw[k * HH + t];
    cond[(size_t)r * HH + t] = mctx[(size_t)ci * HH + t] + acc;
    out0[(size_t)r * HH + t] = mtgt[(size_t)ti * HH + t];
}

// ---------------- small GEMM: y = x @ W + b ----------------
__global__ void k_gemm_h(const float* __restrict__ x, const float* __restrict__ W,
                         const float* __restrict__ b, float* __restrict__ y) {
    int r = blockIdx.x;
    int t = threadIdx.x;  // 128
    __shared__ float xr[HH];
    xr[t] = x[(size_t)r * HH + t];
    __syncthreads();
    float acc = b[t];
#pragma unroll 8
    for (int k = 0; k < HH; k++) acc += xr[k] * W[k * HH + t];
    y[(size_t)r * HH + t] = acc;
}

// ---------------- batchnorm stats per column (biased var) ----------------
__global__ void k_bn_stats(const float* __restrict__ x, float* __restrict__ stats, int rows) {
    int c = blockIdx.x;
    int t = threadIdx.x;  // 256
    float s = 0.f, sq = 0.f;
    for (int r = t; r < rows; r += 256) {
        float v = x[(size_t)r * HH + c];
        s += v; sq += v * v;
    }
    __shared__ float bs[256], bq[256];
    bs[t] = s; bq[t] = sq;
    __syncthreads();
    for (int o = 128; o > 0; o >>= 1) {
        if (t < o) { bs[t] += bs[t + o]; bq[t] += bq[t + o]; }
        __syncthreads();
    }
    if (t == 0) {
        float m = bs[0] / rows;
        float var = bq[0] / rows - m * m;
        stats[c] = m;
        stats[HH + c] = rsqrtf(var + 1e-5f);
    }
}

// ---------------- apply BN + relu in place ----------------
__global__ void k_bn_relu(float* __restrict__ x, const float* __restrict__ stats,
                          const float* __restrict__ g, const float* __restrict__ be, int rows) {
    int gid = blockIdx.x * 256 + threadIdx.x;
    if (gid >= rows * HH) return;
    int c = gid & 127;
    float v = (x[gid] - stats[c]) * stats[HH + c] * g[c] + be[c];
    x[gid] = fmaxf(v, 0.f);
}

extern "C" void kernel_launch(void* const* d_in, const int* in_sizes, int n_in,
                              void* d_out, int out_size, void* d_ws, size_t ws_size,
                              hipStream_t stream) {
    (void)in_sizes; (void)n_in;
    const float* x      = (const float*)d_in[0];
    const float* rw     = (const float*)d_in[1];
    const int*   eidx   = (const int*)d_in[3];
    const float* eattr  = (const float*)d_in[4];
    const float* ew     = (const float*)d_in[5];
    const float* ppe    = (const float*)d_in[6];
    const int*   nmap   = (const int*)d_in[7];
    const int*   csub   = (const int*)d_in[8];
    const int*   semap  = (const int*)d_in[9];
    const int*   sbatch = (const int*)d_in[10];
    const int*   cidx   = (const int*)d_in[11];
    const int*   tgts   = (const int*)d_in[12];
    const float* Win  = (const float*)d_in[14]; const float* bin  = (const float*)d_in[15];
    const float* Wrw  = (const float*)d_in[16]; const float* brw  = (const float*)d_in[17];
    const float* Wprw = (const float*)d_in[18]; const float* bprw = (const float*)d_in[19];
    const float* cWe  = (const float*)d_in[20]; const float* cbe  = (const float*)d_in[21];
    const float* cWl  = (const float*)d_in[22]; const float* cbl  = (const float*)d_in[23];
    const float* tWe  = (const float*)d_in[24]; const float* tbe  = (const float*)d_in[25];
    const float* tWl  = (const float*)d_in[26]; const float* tbl  = (const float*)d_in[27];
    const float* Wp1  = (const float*)d_in[28]; const float* bp1  = (const float*)d_in[29];
    const float* g1   = (const float*)d_in[30]; const float* be1  = (const float*)d_in[31];
    const float* Wp2  = (const float*)d_in[32]; const float* bp2  = (const float*)d_in[33];
    const float* g2   = (const float*)d_in[34]; const float* be2  = (const float*)d_in[35];
    const float* Wp3  = (const float*)d_in[36]; const float* bp3  = (const float*)d_in[37];
    float* out = (float*)d_out;

    // ---- workspace layout (bytes) ----
    // buf0: 102,400,000 B  (x0 f32 [N,128]  | later context h ping-pong bf16 [NS,128])
    // buf1: 102,400,000 B  (target agg f32  | re-encoded x0 f32 | context h ping-pong bf16)
    // buf2:  51,200,000 B  (context agg chunk f32 [CH,128])
    // heads: mctx/mtgt (4096*128 f32), bufc/a/b (2048*128 f32), stats
    const size_t B01  = (size_t)cN * HH * sizeof(float);   // 102,400,000
    const size_t B2   = (size_t)cCH * HH * sizeof(float);  //  51,200,000
    const size_t Bhd  = ((size_t)cNP * HH * 2 + (size_t)2048 * HH * 3 + 256) * sizeof(float);
    const size_t need = B01 * 2 + B2 + Bhd;
    if (ws_size < need) {
        k_diag<<<(out_size + 255) / 256, 256, 0, stream>>>(out, out_size,
                                                           (float)(ws_size >> 20));
        return;
    }

    char* base = (char*)d_ws;
    float* buf0f = (float*)base;                        // f32 view of buf0
    float* buf1f = (float*)(base + B01);                // f32 view of buf1
    unsigned short* buf0h = (unsigned short*)base;      // bf16 view of buf0
    unsigned short* buf1h = (unsigned short*)(base + B01);
    float* aggc = (float*)(base + 2 * B01);             // buf2
    float* mctx = (float*)(base + 2 * B01 + B2);
    float* mtgt = mctx + (size_t)cNP * HH;
    float* bufc = mtgt + (size_t)cNP * HH;
    float* bufa = bufc + (size_t)2048 * HH;
    float* bufb = bufa + (size_t)2048 * HH;
    float* stats = bufb + (size_t)2048 * HH;

    const int msg_grid_f = (int)(((size_t)cE  * HH) / 256);  // 400000
    const int msg_grid_s = (int)(((size_t)cES * HH) / 256);  // 800000

    // ---- phase 1: target branch, all f32 (h in buf0, agg in buf1) ----
    k_node_encode<<<cN, 128, 0, stream>>>(x, rw, Win, bin, Wrw, brw, buf0f);
    for (int l = 0; l < cL; l++) {
        k_zero<<<2048, 256, 0, stream>>>((float4*)buf1f, (size_t)cN * HH / 4);
        k_msg_f32<<<msg_grid_f, 256, 0, stream>>>(buf0f, eidx, eidx + cE, eattr, ew,
                                                  tWe, tbe, buf1f, cE);
        k_layer_gemm<<<cN / 32, 256, 0, stream>>>(buf0f, buf1f,
                                                  tWl + (size_t)l * 2 * HH * HH, tbl + l * HH);
    }
    k_seg_mean_f32<<<cNP, 128, 0, stream>>>(buf0f, nmap, sbatch, mtgt, cNS);

    // ---- phase 2: re-encode x0 into buf1 (f32), gather bf16 h0 into buf0 ----
    k_node_encode<<<cN, 128, 0, stream>>>(x, rw, Win, bin, Wrw, brw, buf1f);
    k_gather_bf16<<<(int)(((size_t)cNS * HH) / 256), 256, 0, stream>>>(buf1f, nmap, buf0h, cNS);

    // ---- phase 3: context branch, bf16 h ping-pong + chunked f32 agg ----
    unsigned short* hold = buf0h;
    unsigned short* hnew = buf1h;
    for (int l = 0; l < cL; l++) {
        const float* W = cWl + (size_t)l * 2 * HH * HH;
        const float* bb = cbl + l * HH;
        for (int c = 0; c < 4; c++) {
            int r0 = c * cCH;
            k_zero<<<2048, 256, 0, stream>>>((float4*)aggc, (size_t)cCH * HH / 4);
            k_msg_ctx<<<msg_grid_s, 256, 0, stream>>>(hold, csub, csub + cES, eattr, semap,
                                                      ew, cWe, cbe, aggc, r0, r0 + cCH, cES);
            k_layer_gemm_ctx<<<cCH / 32, 256, 0, stream>>>(hold, aggc, r0, hnew, W, bb);
        }
        unsigned short* tmp = hold; hold = hnew; hnew = tmp;
    }
    k_seg_mean_bf16<<<cNP, 128, 0, stream>>>(hold, sbatch, mctx, cNS);

    // ---- predictor head ----
    k_cond<<<cB * cPT, 128, 0, stream>>>(mctx, mtgt, cidx, tgts, ppe, Wprw, bprw, bufc, out);
    k_gemm_h<<<2048, 128, 0, stream>>>(bufc, Wp1, bp1, bufa);
    k_bn_stats<<<HH, 256, 0, stream>>>(bufa, stats, 2048);
    k_bn_relu<<<(2048 * HH) / 256, 256, 0, stream>>>(bufa, stats, g1, be1, 2048);
    k_gemm_h<<<2048, 128, 0, stream>>>(bufa, Wp2, bp2, bufb);
    k_bn_stats<<<HH, 256, 0, stream>>>(bufb, stats, 2048);
    k_bn_relu<<<(2048 * HH) / 256, 256, 0, stream>>>(bufb, stats, g2, be2, 2048);
    k_gemm_h<<<2048, 128, 0, stream>>>(bufb, Wp3, bp3, out + (size_t)2048 * HH);
}

// Round 5
// 8285.632 us; speedup vs baseline: 1.5983x; 1.5983x over previous
//
#include <hip/hip_runtime.h>

#define HH 128
constexpr int cN   = 200000;
constexpr int cE   = 800000;
constexpr int cNS  = 400000;
constexpr int cES  = 1600000;
constexpr int cB   = 512;
constexpr int cPPG = 8;
constexpr int cPT  = 4;
constexpr int cNP  = cB * cPPG;     // 4096 patches
constexpr int cNF  = 64;
constexpr int cNE  = 16;
constexpr int cRW  = 16;
constexpr int cPRW = 16;
constexpr int cL   = 4;

__device__ __forceinline__ float b2f(unsigned short b) {
    return __uint_as_float(((unsigned int)b) << 16);
}
__device__ __forceinline__ unsigned short f2b(float f) {
    unsigned int u = __float_as_uint(f);
    return (unsigned short)((u + 0x7fffu + ((u >> 16) & 1u)) >> 16);  // RNE
}

// ---------------- diagnostic ----------------
__global__ void k_diag(float* __restrict__ out, int n, float val) {
    int gid = blockIdx.x * 256 + threadIdx.x;
    if (gid < n) out[gid] = val;
}

__global__ void k_zero_int(int* __restrict__ p, int n) {
    int i = blockIdx.x * 256 + threadIdx.x;
    if (i < n) p[i] = 0;
}
__global__ void k_copy_int(const int* __restrict__ a, int* __restrict__ b, int n) {
    int i = blockIdx.x * 256 + threadIdx.x;
    if (i < n) b[i] = a[i];
}

// ---------------- CSR build ----------------
__global__ void k_hist(const int* __restrict__ dst, int* __restrict__ cnt, int ne) {
    int e = blockIdx.x * 256 + threadIdx.x;
    if (e < ne) atomicAdd(&cnt[dst[e]], 1);
}

// local inclusive scan of cnt -> rp1[i] (= rp+1), block totals -> bsum
__global__ void k_scan_local(const int* __restrict__ cnt, int* __restrict__ rp1,
                             int* __restrict__ bsum, int n) {
    __shared__ int s[256];
    int t = threadIdx.x;
    int i = blockIdx.x * 256 + t;
    s[t] = (i < n) ? cnt[i] : 0;
    __syncthreads();
    for (int off = 1; off < 256; off <<= 1) {
        int u = (t >= off) ? s[t - off] : 0;
        __syncthreads();
        s[t] += u;
        __syncthreads();
    }
    if (i < n) rp1[i] = s[t];
    if (t == 255) bsum[blockIdx.x] = s[255];
}

// single-block inclusive scan of bsum (nb <= ~1600)
__global__ void k_scan_bsums(int* __restrict__ bsum, int nb) {
    __shared__ int s[256];
    __shared__ int carry;
    int t = threadIdx.x;
    if (t == 0) carry = 0;
    __syncthreads();
    for (int base = 0; base < nb; base += 256) {
        int i = base + t;
        s[t] = (i < nb) ? bsum[i] : 0;
        __syncthreads();
        for (int off = 1; off < 256; off <<= 1) {
            int u = (t >= off) ? s[t - off] : 0;
            __syncthreads();
            s[t] += u;
            __syncthreads();
        }
        int c = carry;
        if (i < nb) bsum[i] = s[t] + c;
        __syncthreads();
        if (t == 0) carry = c + s[255];
        __syncthreads();
    }
}

__global__ void k_rp_finalize(const int* __restrict__ bsum, int* __restrict__ rp, int n) {
    int i = blockIdx.x * 256 + threadIdx.x;
    if (i == 0) rp[0] = 0;
    if (i < n) {
        int blk = i >> 8;
        rp[i + 1] += blk ? bsum[blk - 1] : 0;
    }
}

// scatter edges into dst-sorted order; ais = original attr index (emap[e] or e)
__global__ void k_scatter(const int* __restrict__ src, const int* __restrict__ dst,
                          const int* __restrict__ emap, int* __restrict__ cursor,
                          int* __restrict__ srcs, int* __restrict__ ais, int ne) {
    int e = blockIdx.x * 256 + threadIdx.x;
    if (e >= ne) return;
    int p = atomicAdd(&cursor[dst[e]], 1);
    srcs[p] = src[e];
    ais[p] = emap ? emap[e] : e;
}

// ---------------- node encoder: x0 = x@Win + bin + rw@Wrw + brw (f32 out) ----------------
__global__ void k_node_encode(const float* __restrict__ x, const float* __restrict__ rw,
                              const float* __restrict__ Win, const float* __restrict__ bin,
                              const float* __restrict__ Wrw, const float* __restrict__ brw,
                              float* __restrict__ x0) {
    __shared__ float sx[cNF];
    __shared__ float srw[cRW];
    int node = blockIdx.x;
    int t = threadIdx.x;  // 128
    if (t < cNF) sx[t] = x[(size_t)node * cNF + t];
    else if (t < cNF + cRW) srw[t - cNF] = rw[(size_t)node * cRW + (t - cNF)];
    __syncthreads();
    float acc = bin[t] + brw[t];
#pragma unroll
    for (int k = 0; k < cNF; k++) acc += sx[k] * Win[k * HH + t];
#pragma unroll
    for (int k = 0; k < cRW; k++) acc += srw[k] * Wrw[k * HH + t];
    x0[(size_t)node * HH + t] = acc;
}

// encoder fused with row gather, bf16 out: out[i] = bf16(encode(x[map[i]], rw[map[i]]))
__global__ void k_encode_gather_bf16(const float* __restrict__ x, const float* __restrict__ rw,
                                     const int* __restrict__ map,
                                     const float* __restrict__ Win, const float* __restrict__ bin,
                                     const float* __restrict__ Wrw, const float* __restrict__ brw,
                                     unsigned short* __restrict__ out) {
    __shared__ float sx[cNF];
    __shared__ float srw[cRW];
    int node = map[blockIdx.x];
    int t = threadIdx.x;  // 128
    if (t < cNF) sx[t] = x[(size_t)node * cNF + t];
    else if (t < cNF + cRW) srw[t - cNF] = rw[(size_t)node * cRW + (t - cNF)];
    __syncthreads();
    float acc = bin[t] + brw[t];
#pragma unroll
    for (int k = 0; k < cNF; k++) acc += sx[k] * Win[k * HH + t];
#pragma unroll
    for (int k = 0; k < cRW; k++) acc += srw[k] * Wrw[k * HH + t];
    out[(size_t)blockIdx.x * HH + t] = f2b(acc);
}

// ---------------- fused layer: agg-from-CSR + GEMM, ping-pong h ----------------
// h_new = relu(concat(h_old, agg) @ W + b), agg[r] = sum_{e in CSR[r]} (h_old[src]+relu(ea@We+be))*w
template <bool BF16>
__global__ void __launch_bounds__(256)
k_layer_fused(const void* __restrict__ h_in_v, void* __restrict__ h_out_v,
              const int* __restrict__ rp, const int* __restrict__ srcs,
              const int* __restrict__ ais,
              const float* __restrict__ eattr, const float* __restrict__ ew,
              const float* __restrict__ We, const float* __restrict__ be,
              const float* __restrict__ W, const float* __restrict__ b) {
    __shared__ float a[32][2 * HH];  // 32 KB
    int base = blockIdx.x * 32;
    int t = threadIdx.x;  // 256
    const float* hf = (const float*)h_in_v;
    const unsigned short* hb = (const unsigned short*)h_in_v;

    // A1: stage own h rows into a[r][0..127] (coalesced)
    for (int i = t; i < 32 * HH; i += 256) {
        int r = i >> 7, c = i & 127;
        size_t idx = (size_t)(base + r) * HH + c;
        a[r][c] = BF16 ? b2f(hb[idx]) : hf[idx];
    }
    // A2: compute agg into a[r][128..255]; 2 rows at a time (wave-uniform rows)
    {
        int half = t >> 7;  // 0/1
        int c = t & 127;
        for (int p = 0; p < 16; p++) {
            int r = p * 2 + half;
            int e0 = rp[base + r], e1 = rp[base + r + 1];
            float acc = 0.f;
            for (int e = e0; e < e1; e++) {
                int s = srcs[e];
                int ai = ais[e];
                float w = ew[ai];
                const float* ea = eattr + (size_t)ai * cNE;
                float eh = be[c];
#pragma unroll
                for (int k = 0; k < cNE; k++) eh += ea[k] * We[k * HH + c];
                eh = fmaxf(eh, 0.f);
                float hv = BF16 ? b2f(hb[(size_t)s * HH + c]) : hf[(size_t)s * HH + c];
                acc += (hv + eh) * w;
            }
            a[r][HH + c] = acc;
        }
    }
    __syncthreads();

    // B: 32x128 GEMM, 4x4 per thread
    int cg = t & 31;   // cols cg*4..+3
    int rg = t >> 5;   // rows rg*4..+3
    float acc[4][4];
#pragma unroll
    for (int r = 0; r < 4; r++)
#pragma unroll
        for (int c = 0; c < 4; c++) acc[r][c] = 0.f;
    for (int k = 0; k < 2 * HH; k += 4) {
        float4 av[4];
#pragma unroll
        for (int r = 0; r < 4; r++) av[r] = *(const float4*)&a[rg * 4 + r][k];
        float4 wv[4];
#pragma unroll
        for (int kk = 0; kk < 4; kk++) wv[kk] = *(const float4*)&W[(size_t)(k + kk) * HH + cg * 4];
#pragma unroll
        for (int r = 0; r < 4; r++) {
            float a0 = av[r].x, a1 = av[r].y, a2 = av[r].z, a3 = av[r].w;
            acc[r][0] += a0 * wv[0].x + a1 * wv[1].x + a2 * wv[2].x + a3 * wv[3].x;
            acc[r][1] += a0 * wv[0].y + a1 * wv[1].y + a2 * wv[2].y + a3 * wv[3].y;
            acc[r][2] += a0 * wv[0].z + a1 * wv[1].z + a2 * wv[2].z + a3 * wv[3].z;
            acc[r][3] += a0 * wv[0].w + a1 * wv[1].w + a2 * wv[2].w + a3 * wv[3].w;
        }
    }
    float4 bv = *(const float4*)&b[cg * 4];
#pragma unroll
    for (int r = 0; r < 4; r++) {
        int row = base + rg * 4 + r;
        float o0 = fmaxf(acc[r][0] + bv.x, 0.f);
        float o1 = fmaxf(acc[r][1] + bv.y, 0.f);
        float o2 = fmaxf(acc[r][2] + bv.z, 0.f);
        float o3 = fmaxf(acc[r][3] + bv.w, 0.f);
        if (BF16) {
            ushort4 o = { f2b(o0), f2b(o1), f2b(o2), f2b(o3) };
            *(ushort4*)&((unsigned short*)h_out_v)[(size_t)row * HH + cg * 4] = o;
        } else {
            float4 o = { o0, o1, o2, o3 };
            *(float4*)&((float*)h_out_v)[(size_t)row * HH + cg * 4] = o;
        }
    }
}

// ---------------- segmented mean over sorted batch ----------------
__global__ void k_seg_mean_f32(const float* __restrict__ src, const int* __restrict__ map,
                               const int* __restrict__ batch, float* __restrict__ out, int nrows) {
    int b = blockIdx.x;
    int t = threadIdx.x;  // 128
    int lo = 0, hi = nrows;
    while (lo < hi) { int m = (lo + hi) >> 1; if (batch[m] < b) lo = m + 1; else hi = m; }
    int s = lo;
    hi = nrows;
    while (lo < hi) { int m = (lo + hi) >> 1; if (batch[m] < b + 1) lo = m + 1; else hi = m; }
    int e = lo;
    float acc = 0.f;
    for (int r = s; r < e; r++) {
        size_t row = map ? (size_t)map[r] : (size_t)r;
        acc += src[row * HH + t];
    }
    out[(size_t)b * HH + t] = acc / fmaxf((float)(e - s), 1.f);
}

__global__ void k_seg_mean_bf16(const unsigned short* __restrict__ src,
                                const int* __restrict__ batch, float* __restrict__ out, int nrows) {
    int b = blockIdx.x;
    int t = threadIdx.x;  // 128
    int lo = 0, hi = nrows;
    while (lo < hi) { int m = (lo + hi) >> 1; if (batch[m] < b) lo = m + 1; else hi = m; }
    int s = lo;
    hi = nrows;
    while (lo < hi) { int m = (lo + hi) >> 1; if (batch[m] < b + 1) lo = m + 1; else hi = m; }
    int e = lo;
    float acc = 0.f;
    for (int r = s; r < e; r++) acc += b2f(src[(size_t)r * HH + t]);
    out[(size_t)b * HH + t] = acc / fmaxf((float)(e - s), 1.f);
}

// ---------------- head kernels ----------------
__global__ void k_cond(const float* __restrict__ mctx, const float* __restrict__ mtgt,
                       const int* __restrict__ cidx, const int* __restrict__ tgt_idxs,
                       const float* __restrict__ ppe, const float* __restrict__ Wprw,
                       const float* __restrict__ bprw, float* __restrict__ cond,
                       float* __restrict__ out0) {
    int r = blockIdx.x;   // 0..2047
    int t = threadIdx.x;  // 128
    int bg = r >> 2, tt = r & 3;
    int ti = tgt_idxs[bg * cPT + tt] + bg * cPPG;
    int ci = cidx[bg] + bg * cPPG;
    __shared__ float pe[cPRW];
    if (t < cPRW) pe[t] = ppe[(size_t)ti * cPRW + t];
    __syncthreads();
    float acc = bprw[t];
#pragma unroll
    for (int k = 0; k < cPRW; k++) acc += pe[k] * Wprw[k * HH + t];
    cond[(size_t)r * HH + t] = mctx[(size_t)ci * HH + t] + acc;
    out0[(size_t)r * HH + t] = mtgt[(size_t)ti * HH + t];
}

__global__ void k_gemm_h(const float* __restrict__ x, const float* __restrict__ W,
                         const float* __restrict__ b, float* __restrict__ y) {
    int r = blockIdx.x;
    int t = threadIdx.x;  // 128
    __shared__ float xr[HH];
    xr[t] = x[(size_t)r * HH + t];
    __syncthreads();
    float acc = b[t];
#pragma unroll 8
    for (int k = 0; k < HH; k++) acc += xr[k] * W[k * HH + t];
    y[(size_t)r * HH + t] = acc;
}

__global__ void k_bn_stats(const float* __restrict__ x, float* __restrict__ stats, int rows) {
    int c = blockIdx.x;
    int t = threadIdx.x;  // 256
    float s = 0.f, sq = 0.f;
    for (int r = t; r < rows; r += 256) {
        float v = x[(size_t)r * HH + c];
        s += v; sq += v * v;
    }
    __shared__ float bs[256], bq[256];
    bs[t] = s; bq[t] = sq;
    __syncthreads();
    for (int o = 128; o > 0; o >>= 1) {
        if (t < o) { bs[t] += bs[t + o]; bq[t] += bq[t + o]; }
        __syncthreads();
    }
    if (t == 0) {
        float m = bs[0] / rows;
        float var = bq[0] / rows - m * m;
        stats[c] = m;
        stats[HH + c] = rsqrtf(var + 1e-5f);
    }
}

__global__ void k_bn_relu(float* __restrict__ x, const float* __restrict__ stats,
                          const float* __restrict__ g, const float* __restrict__ be, int rows) {
    int gid = blockIdx.x * 256 + threadIdx.x;
    if (gid >= rows * HH) return;
    int c = gid & 127;
    float v = (x[gid] - stats[c]) * stats[HH + c] * g[c] + be[c];
    x[gid] = fmaxf(v, 0.f);
}

// ---------------- CSR build driver (host-side helper) ----------------
static void build_csr(const int* src, const int* dst, const int* emap, int nnodes, int ne,
                      int* rp, int* srcs, int* ais, int* cursor, int* bsum,
                      hipStream_t stream) {
    int nb = (nnodes + 255) / 256;
    k_zero_int<<<nb, 256, 0, stream>>>(cursor, nnodes);          // use cursor as cnt
    k_hist<<<(ne + 255) / 256, 256, 0, stream>>>(dst, cursor, ne);
    k_scan_local<<<nb, 256, 0, stream>>>(cursor, rp + 1, bsum, nnodes);
    k_scan_bsums<<<1, 256, 0, stream>>>(bsum, nb);
    k_rp_finalize<<<nb, 256, 0, stream>>>(bsum, rp, nnodes);
    k_copy_int<<<nb, 256, 0, stream>>>(rp, cursor, nnodes);
    k_scatter<<<(ne + 255) / 256, 256, 0, stream>>>(src, dst, emap, cursor, srcs, ais, ne);
}

extern "C" void kernel_launch(void* const* d_in, const int* in_sizes, int n_in,
                              void* d_out, int out_size, void* d_ws, size_t ws_size,
                              hipStream_t stream) {
    (void)in_sizes; (void)n_in;
    const float* x      = (const float*)d_in[0];
    const float* rw     = (const float*)d_in[1];
    const int*   eidx   = (const int*)d_in[3];
    const float* eattr  = (const float*)d_in[4];
    const float* ew     = (const float*)d_in[5];
    const float* ppe    = (const float*)d_in[6];
    const int*   nmap   = (const int*)d_in[7];
    const int*   csub   = (const int*)d_in[8];
    const int*   semap  = (const int*)d_in[9];
    const int*   sbatch = (const int*)d_in[10];
    const int*   cidx   = (const int*)d_in[11];
    const int*   tgts   = (const int*)d_in[12];
    const float* Win  = (const float*)d_in[14]; const float* bin  = (const float*)d_in[15];
    const float* Wrw  = (const float*)d_in[16]; const float* brw  = (const float*)d_in[17];
    const float* Wprw = (const float*)d_in[18]; const float* bprw = (const float*)d_in[19];
    const float* cWe  = (const float*)d_in[20]; const float* cbe  = (const float*)d_in[21];
    const float* cWl  = (const float*)d_in[22]; const float* cbl  = (const float*)d_in[23];
    const float* tWe  = (const float*)d_in[24]; const float* tbe  = (const float*)d_in[25];
    const float* tWl  = (const float*)d_in[26]; const float* tbl  = (const float*)d_in[27];
    const float* Wp1  = (const float*)d_in[28]; const float* bp1  = (const float*)d_in[29];
    const float* g1   = (const float*)d_in[30]; const float* be1  = (const float*)d_in[31];
    const float* Wp2  = (const float*)d_in[32]; const float* bp2  = (const float*)d_in[33];
    const float* g2   = (const float*)d_in[34]; const float* be2  = (const float*)d_in[35];
    const float* Wp3  = (const float*)d_in[36]; const float* bp3  = (const float*)d_in[37];
    float* out = (float*)d_out;

    // ---- workspace layout ----
    // R0, R1: 102,400,000 B each (target h f32 [N,128] ping-pong; later ctx h bf16 [NS,128])
    // CSR region + head buffers after.
    const size_t R = (size_t)cN * HH * sizeof(float);  // 102,400,000
    char* base = (char*)d_ws;
    float* R0f = (float*)base;
    float* R1f = (float*)(base + R);
    unsigned short* R0h = (unsigned short*)base;
    unsigned short* R1h = (unsigned short*)(base + R);
    int* ip = (int*)(base + 2 * R);
    int* rp_t  = ip;  ip += cN + 1;
    int* rp_c  = ip;  ip += cNS + 1;
    int* src_t = ip;  ip += cE;
    int* ai_t  = ip;  ip += cE;
    int* src_c = ip;  ip += cES;
    int* ai_c  = ip;  ip += cES;
    int* cursor = ip; ip += cNS;
    int* bsum  = ip;  ip += 2048;
    float* fp  = (float*)ip;
    float* mctx = fp; fp += (size_t)cNP * HH;
    float* mtgt = fp; fp += (size_t)cNP * HH;
    float* bufc = fp; fp += (size_t)2048 * HH;
    float* bufa = fp; fp += (size_t)2048 * HH;
    float* bufb = fp; fp += (size_t)2048 * HH;
    float* stats = fp; fp += 256;
    const size_t need = (size_t)((char*)fp - base);
    if (ws_size < need) {
        k_diag<<<(out_size + 255) / 256, 256, 0, stream>>>(out, out_size,
                                                           (float)(ws_size >> 20));
        return;
    }

    // ---- phase 0: build both CSRs (graph-static, h-independent) ----
    build_csr(eidx, eidx + cE, nullptr, cN, cE, rp_t, src_t, ai_t, cursor, bsum, stream);
    build_csr(csub, csub + cES, semap, cNS, cES, rp_c, src_c, ai_c, cursor, bsum, stream);

    // ---- phase 1: target branch, f32 ping-pong R0 <-> R1 ----
    k_node_encode<<<cN, 128, 0, stream>>>(x, rw, Win, bin, Wrw, brw, R0f);
    {
        void* hp[2] = { (void*)R0f, (void*)R1f };
        for (int l = 0; l < cL; l++) {
            k_layer_fused<false><<<cN / 32, 256, 0, stream>>>(
                hp[l & 1], hp[(l & 1) ^ 1], rp_t, src_t, ai_t, eattr, ew, tWe, tbe,
                tWl + (size_t)l * 2 * HH * HH, tbl + l * HH);
        }
    }
    // 4 layers -> final in R0f
    k_seg_mean_f32<<<cNP, 128, 0, stream>>>(R0f, nmap, sbatch, mtgt, cNS);

    // ---- phase 2: context branch, bf16 ping-pong R0h <-> R1h ----
    k_encode_gather_bf16<<<cNS, 128, 0, stream>>>(x, rw, nmap, Win, bin, Wrw, brw, R0h);
    {
        void* hp[2] = { (void*)R0h, (void*)R1h };
        for (int l = 0; l < cL; l++) {
            k_layer_fused<true><<<cNS / 32, 256, 0, stream>>>(
                hp[l & 1], hp[(l & 1) ^ 1], rp_c, src_c, ai_c, eattr, ew, cWe, cbe,
                cWl + (size_t)l * 2 * HH * HH, cbl + l * HH);
        }
    }
    k_seg_mean_bf16<<<cNP, 128, 0, stream>>>(R0h, sbatch, mctx, cNS);

    // ---- predictor head ----
    k_cond<<<cB * cPT, 128, 0, stream>>>(mctx, mtgt, cidx, tgts, ppe, Wprw, bprw, bufc, out);
    k_gemm_h<<<2048, 128, 0, stream>>>(bufc, Wp1, bp1, bufa);
    k_bn_stats<<<HH, 256, 0, stream>>>(bufa, stats, 2048);
    k_bn_relu<<<(2048 * HH) / 256, 256, 0, stream>>>(bufa, stats, g1, be1, 2048);
    k_gemm_h<<<2048, 128, 0, stream>>>(bufa, Wp2, bp2, bufb);
    k_bn_stats<<<HH, 256, 0, stream>>>(bufb, stats, 2048);
    k_bn_relu<<<(2048 * HH) / 256, 256, 0, stream>>>(bufb, stats, g2, be2, 2048);
    k_gemm_h<<<2048, 128, 0, stream>>>(bufb, Wp3, bp3, out + (size_t)2048 * HH);
}